// Round 8
// baseline (27.000 us; speedup 1.0000x reference)
//
#include <hip/hip_runtime.h>
#include <hip/hip_bf16.h>

// HungarianMatcher cost matrix:
//   C[i, j] = 10 * L1(pred_pts[i], gt_pts[j])
//           + 2 * (pos_cost - neg_cost)(sigmoid(pred_class[i, tid_j]))
// i in [0, bs*Q=8192), j in [0, bs*T=4096), num_classes = 2.
//
// R8: R7's flat memset-shaped stream, but at fill-kernel-like concurrency:
// 256 blocks x 256 threads (1 block/CU, 4 waves/CU — the 6.85 TB/s rocclr
// fill runs ~3 waves/CU), ITERS=128. Chip-wide contiguous window per
// iteration step shrinks 4 MB -> 1 MB (tighter DRAM page locality), and the
// number of concurrently-open wave streams drops 4096 -> 1024.
// Column stays loop-invariant per thread (targets in registers, 3 loads
// total); row per iter is thread-uniform (one LDS float4 broadcast).

#define ALPHA  0.25f
#define EPS_F  1e-8f
#define CLS_W  2.0f

typedef float f32x4 __attribute__((ext_vector_type(4)));

__device__ __forceinline__ float focal_cc(float x) {
    // p = sigmoid(x); returns CLS_W * (pos_cost - neg_cost), gamma = 2
    float p  = 1.0f / (1.0f + expf(-x));
    float om = 1.0f - p;
    float pos = ALPHA          * om * om * (-logf(p  + EPS_F));
    float neg = (1.0f - ALPHA) * p  * p  * (-logf(om + EPS_F));
    return CLS_W * (pos - neg);
}

template <int ITERS>
__global__ __launch_bounds__(256)
void hm_cost_kernel(const float2* __restrict__ pred_class,  // [rows] (2 classes)
                    const float2* __restrict__ pred_pts,    // [rows]
                    const int*    __restrict__ tgt_ids,     // [cols]
                    const float2* __restrict__ tgt_pts,     // [cols]
                    float*        __restrict__ out,         // [rows, cols]
                    int cols4,      // cols/4 = 1024
                    int row_step) { // gridDim*blockDim/cols4 = 64
    const int b   = blockIdx.x;
    const int tid = threadIdx.x;
    const int T   = blockDim.x;                  // 256

    // Rows touched by this block: rbase + row_step*i, i in [0, ITERS).
    // (b*T + tid)/cols4 is tid-invariant because b*T % cols4 + T <= cols4.
    const int rbase = (b * T) / cols4;

    // s_row[i] = {px, py, cc0, cc1} for row rbase + row_step*i
    __shared__ float4 s_row[ITERS];
    if (tid < 2 * ITERS) {
        const int i = tid >> 1, c = tid & 1;
        const int r = rbase + i * row_step;
        const float2 x = pred_class[r];
        ((float*)&s_row[i])[2 + c] = focal_cc(c ? x.y : x.x);
        if (c == 0) {
            const float2 pt = pred_pts[r];
            s_row[i].x = pt.x;
            s_row[i].y = pt.y;
        }
    }
    __syncthreads();

    // Loop-invariant target data for this thread's fixed column group.
    const int col4 = (b * T + tid) % cols4;
    const float4* tp4 = reinterpret_cast<const float4*>(tgt_pts);
    const int4*   id4 = reinterpret_cast<const int4*>(tgt_ids);
    const float4 tpA = tp4[col4 * 2 + 0];        // tx0, ty0, tx1, ty1
    const float4 tpB = tp4[col4 * 2 + 1];        // tx2, ty2, tx3, ty3
    const int4   id  = id4[col4];

    f32x4* out4 = reinterpret_cast<f32x4*>(out);
    size_t idx = (size_t)b * T + tid;            // float4 units
    const size_t stride = (size_t)gridDim.x * T; // 65536 float4 = 1 MB

#pragma unroll 4
    for (int i = 0; i < ITERS; ++i) {
        const float4 s = s_row[i];               // LDS broadcast (wave-uniform)
        const float qx = s.x, qy = s.y, c0 = s.z, c1 = s.w;
        f32x4 o;
        o.x = 10.0f * (fabsf(qx - tpA.x) + fabsf(qy - tpA.y)) + (id.x ? c1 : c0);
        o.y = 10.0f * (fabsf(qx - tpA.z) + fabsf(qy - tpA.w)) + (id.y ? c1 : c0);
        o.z = 10.0f * (fabsf(qx - tpB.x) + fabsf(qy - tpB.y)) + (id.z ? c1 : c0);
        o.w = 10.0f * (fabsf(qx - tpB.z) + fabsf(qy - tpB.w)) + (id.w ? c1 : c0);
        out4[idx] = o;
        idx += stride;
    }
}

extern "C" void kernel_launch(void* const* d_in, const int* in_sizes, int n_in,
                              void* d_out, int out_size, void* d_ws, size_t ws_size,
                              hipStream_t stream) {
    // inputs: pred_class [bs,Q,2] f32, pred_points [bs,Q,2] f32,
    //         gt_class [bs,T] int32, gt_points [bs,T,2] f32
    const float2* pred_class = reinterpret_cast<const float2*>(d_in[0]);
    const float2* pred_pts   = reinterpret_cast<const float2*>(d_in[1]);
    const int*    tgt_ids    = reinterpret_cast<const int*>(d_in[2]);
    const float2* tgt_pts    = reinterpret_cast<const float2*>(d_in[3]);
    float*        out        = reinterpret_cast<float*>(d_out);

    const int rows  = in_sizes[1] / 2;   // bs*Q = 8192
    const int cols  = in_sizes[2];       // bs*T = 4096
    const int cols4 = cols / 4;          // 1024

    constexpr int ITERS = 128;
    constexpr int T = 256;
    const int total4 = rows * cols4;                 // 8.39M float4
    const int grid   = total4 / (T * ITERS);         // 256 blocks
    const int row_step = (grid * T) / cols4;         // 64
    hm_cost_kernel<ITERS><<<grid, T, 0, stream>>>(
        pred_class, pred_pts, tgt_ids, tgt_pts, out, cols4, row_step);
}

// Round 9
// 26.472 us; speedup vs baseline: 1.0199x; 1.0199x over previous
//
#include <hip/hip_runtime.h>
#include <hip/hip_bf16.h>

// HungarianMatcher cost matrix:
//   C[i, j] = 10 * L1(pred_pts[i], gt_pts[j])
//           + 2 * (pos_cost - neg_cost)(sigmoid(pred_class[i, tid_j]))
// i in [0, bs*Q=8192), j in [0, bs*T=4096), num_classes = 2.
//
// R9: R7's flat memset-shaped stream at MAX store concurrency:
// 1024 blocks x 512 threads (4 blocks/CU, 32 waves/CU), ITERS=16.
// Evidence: R7 (16 w/CU) 25.96us > R8 (4 w/CU) 27.0us > R6-null — deeper
// outstanding-store queues shorten the ramp that dominates the gap to the
// 6.9 TB/s fill-kernel asymptote. Column stays loop-invariant per thread
// (targets in 3 registers); row per iter is thread-uniform (LDS broadcast).

#define ALPHA  0.25f
#define EPS_F  1e-8f
#define CLS_W  2.0f

typedef float f32x4 __attribute__((ext_vector_type(4)));

__device__ __forceinline__ float focal_cc(float x) {
    // p = sigmoid(x); returns CLS_W * (pos_cost - neg_cost), gamma = 2
    float p  = 1.0f / (1.0f + expf(-x));
    float om = 1.0f - p;
    float pos = ALPHA          * om * om * (-logf(p  + EPS_F));
    float neg = (1.0f - ALPHA) * p  * p  * (-logf(om + EPS_F));
    return CLS_W * (pos - neg);
}

template <int ITERS>
__global__ __launch_bounds__(512)
void hm_cost_kernel(const float2* __restrict__ pred_class,  // [rows] (2 classes)
                    const float2* __restrict__ pred_pts,    // [rows]
                    const int*    __restrict__ tgt_ids,     // [cols]
                    const float2* __restrict__ tgt_pts,     // [cols]
                    float*        __restrict__ out,         // [rows, cols]
                    int cols4,      // cols/4 = 1024
                    int row_step) { // gridDim*blockDim/cols4 = 512
    const int b   = blockIdx.x;
    const int tid = threadIdx.x;
    const int T   = blockDim.x;                  // 512

    // Rows touched by this block: rbase + row_step*i, i in [0, ITERS).
    // (b*T + tid)/cols4 is tid-invariant because b*T % cols4 + T <= cols4.
    const int rbase = (b * T) / cols4;

    // s_row[i] = {px, py, cc0, cc1} for row rbase + row_step*i
    __shared__ float4 s_row[ITERS];
    if (tid < 2 * ITERS) {
        const int i = tid >> 1, c = tid & 1;
        const int r = rbase + i * row_step;
        const float2 x = pred_class[r];
        ((float*)&s_row[i])[2 + c] = focal_cc(c ? x.y : x.x);
        if (c == 0) {
            const float2 pt = pred_pts[r];
            s_row[i].x = pt.x;
            s_row[i].y = pt.y;
        }
    }
    __syncthreads();

    // Loop-invariant target data for this thread's fixed column group.
    const int col4 = (b * T + tid) % cols4;
    const float4* tp4 = reinterpret_cast<const float4*>(tgt_pts);
    const int4*   id4 = reinterpret_cast<const int4*>(tgt_ids);
    const float4 tpA = tp4[col4 * 2 + 0];        // tx0, ty0, tx1, ty1
    const float4 tpB = tp4[col4 * 2 + 1];        // tx2, ty2, tx3, ty3
    const int4   id  = id4[col4];

    f32x4* out4 = reinterpret_cast<f32x4*>(out);
    size_t idx = (size_t)b * T + tid;            // float4 units
    const size_t stride = (size_t)gridDim.x * T; // 524288 float4 = 8 MB

#pragma unroll 4
    for (int i = 0; i < ITERS; ++i) {
        const float4 s = s_row[i];               // LDS broadcast (wave-uniform)
        const float qx = s.x, qy = s.y, c0 = s.z, c1 = s.w;
        f32x4 o;
        o.x = 10.0f * (fabsf(qx - tpA.x) + fabsf(qy - tpA.y)) + (id.x ? c1 : c0);
        o.y = 10.0f * (fabsf(qx - tpA.z) + fabsf(qy - tpA.w)) + (id.y ? c1 : c0);
        o.z = 10.0f * (fabsf(qx - tpB.x) + fabsf(qy - tpB.y)) + (id.z ? c1 : c0);
        o.w = 10.0f * (fabsf(qx - tpB.z) + fabsf(qy - tpB.w)) + (id.w ? c1 : c0);
        out4[idx] = o;
        idx += stride;
    }
}

extern "C" void kernel_launch(void* const* d_in, const int* in_sizes, int n_in,
                              void* d_out, int out_size, void* d_ws, size_t ws_size,
                              hipStream_t stream) {
    // inputs: pred_class [bs,Q,2] f32, pred_points [bs,Q,2] f32,
    //         gt_class [bs,T] int32, gt_points [bs,T,2] f32
    const float2* pred_class = reinterpret_cast<const float2*>(d_in[0]);
    const float2* pred_pts   = reinterpret_cast<const float2*>(d_in[1]);
    const int*    tgt_ids    = reinterpret_cast<const int*>(d_in[2]);
    const float2* tgt_pts    = reinterpret_cast<const float2*>(d_in[3]);
    float*        out        = reinterpret_cast<float*>(d_out);

    const int rows  = in_sizes[1] / 2;   // bs*Q = 8192
    const int cols  = in_sizes[2];       // bs*T = 4096
    const int cols4 = cols / 4;          // 1024

    constexpr int ITERS = 16;
    constexpr int T = 512;
    const int total4 = rows * cols4;                 // 8.39M float4
    const int grid   = total4 / (T * ITERS);         // 1024 blocks
    const int row_step = (grid * T) / cols4;         // 512
    hm_cost_kernel<ITERS><<<grid, T, 0, stream>>>(
        pred_class, pred_pts, tgt_ids, tgt_pts, out, cols4, row_step);
}